// Round 8
// baseline (810.311 us; speedup 1.0000x reference)
//
#include <hip/hip_runtime.h>

#define N_NODES 50000
#define N_EDGES 800000
#define D 128
#define R_REL 4
#define L_LAYERS 3
#define M_SEG (N_NODES * R_REL)
#define NCOLS 384
#define BN_EPS 1e-5f

typedef unsigned short u16;
typedef __attribute__((ext_vector_type(8))) short short8v;
typedef __attribute__((ext_vector_type(4))) float f32x4;

static __device__ __forceinline__ u16 f2b(float f) {
    union { float f; unsigned int u; } a; a.f = f;
    unsigned int u = a.u;
    return (u16)((u + 0x7FFFu + ((u >> 16) & 1u)) >> 16);
}
static __device__ __forceinline__ float b2f(u16 b) {
    union { unsigned int u; float f; } a; a.u = ((unsigned int)b) << 16;
    return a.f;
}

// ---------------- weight packing: Wpb[(l*5+p)][j=0..383][k=0..127] bf16 (transposed)
__global__ void pack_w(const float* __restrict__ Wsk, const float* __restrict__ Wfsk,
                       const float* __restrict__ Wr, const float* __restrict__ Wf,
                       u16* __restrict__ Wpb) {
    int idx = blockIdx.x * 256 + threadIdx.x;
    if (idx >= L_LAYERS * 5 * NCOLS * D) return;
    int k = idx & 127;
    int rem = idx >> 7;
    int j = rem % NCOLS;
    int lp = rem / NCOLS;
    int l = lp / 5, p = lp % 5;
    float v;
    if (p == 0) {
        v = (j < D) ? Wsk[(l * D + k) * D + j] : Wfsk[(l * D + k) * 2 * D + (j - D)];
    } else {
        int r = p - 1;
        v = (j < D) ? Wr[((l * R_REL + r) * D + k) * D + j]
                    : Wf[((l * R_REL + r) * D + k) * 2 * D + (j - D)];
    }
    Wpb[idx] = f2b(v);
}

__global__ void cvt_bf16(const float* __restrict__ x, u16* __restrict__ xb) {
    int idx = blockIdx.x * 256 + threadIdx.x;
    if (idx >= N_NODES * D) return;
    xb[idx] = f2b(x[idx]);
}

// ---------------- CSR build over segments seg = dst*R + etype (rank captured here)
__global__ void hist_k(const int* __restrict__ dst, const int* __restrict__ et,
                       int* __restrict__ cnt, int* __restrict__ rank) {
    int e = blockIdx.x * 256 + threadIdx.x;
    if (e >= N_EDGES) return;
    rank[e] = atomicAdd(&cnt[dst[e] * R_REL + et[e]], 1);
}

__global__ void scan_a(const int* __restrict__ cnt, int* __restrict__ bsum) {
    __shared__ int sm[256];
    int t = threadIdx.x;
    int idx = blockIdx.x * 256 + t;
    sm[t] = (idx < M_SEG) ? cnt[idx] : 0;
    __syncthreads();
    for (int s = 128; s > 0; s >>= 1) {
        if (t < s) sm[t] += sm[t + s];
        __syncthreads();
    }
    if (t == 0) bsum[blockIdx.x] = sm[0];
}

#define NB_SCAN 782  // ceil(200000/256)
__global__ void scan_b(const int* __restrict__ bsum, int* __restrict__ bsumex, int* __restrict__ offs) {
    __shared__ int sm[1024];
    int t = threadIdx.x;
    int v = (t < NB_SCAN) ? bsum[t] : 0;
    sm[t] = v;
    __syncthreads();
    for (int d = 1; d < 1024; d <<= 1) {
        int add = (t >= d) ? sm[t - d] : 0;
        __syncthreads();
        sm[t] += add;
        __syncthreads();
    }
    if (t < NB_SCAN) bsumex[t] = sm[t] - v;
    if (t == NB_SCAN - 1) offs[M_SEG] = sm[t];
}

__global__ void scan_c(const int* __restrict__ cnt, const int* __restrict__ bsumex, int* __restrict__ offs) {
    __shared__ int sm[256];
    int t = threadIdx.x;
    int idx = blockIdx.x * 256 + t;
    int v = (idx < M_SEG) ? cnt[idx] : 0;
    sm[t] = v;
    __syncthreads();
    for (int d = 1; d < 256; d <<= 1) {
        int add = (t >= d) ? sm[t - d] : 0;
        __syncthreads();
        sm[t] += add;
        __syncthreads();
    }
    if (idx < M_SEG) offs[idx] = bsumex[blockIdx.x] + sm[t] - v;
}

__global__ void scatter_k(const int* __restrict__ src, const int* __restrict__ dst,
                          const int* __restrict__ et, const int* __restrict__ offs,
                          const int* __restrict__ rank, int* __restrict__ esrc) {
    int e = blockIdx.x * 256 + threadIdx.x;
    if (e >= N_EDGES) return;
    int seg = dst[e] * R_REL + et[e];
    esrc[offs[seg] + rank[e]] = src[e];
}

// ============ unified per-layer GEMM, grid (391, 5):
// p<4: relation planes -> xrp[p][N][128] (xr) and gbp[N][p][256] (beta|gamma)
// p==4: self FiLM fused -> selfb[N][128] = relu(gamma_s * xsk + beta_s)
// A fragments direct from global (L2-resident); LDS only for the coalescing epilogue (32 KB).
__global__ __launch_bounds__(512) void gemm_all(const uint4* __restrict__ Aq,
                                                const uint4* __restrict__ Bq,   // layer base [5*384][16]
                                                u16* __restrict__ xrp, u16* __restrict__ gbp,
                                                u16* __restrict__ selfb) {
    __shared__ u16 Cs[128 * 128];
    int t = threadIdx.x;
    int m0 = blockIdx.x * 128;
    int p = blockIdx.y;
    int lane = t & 63, w = t >> 6;
    int wr = w >> 2, wc = w & 3;
    int lr = lane & 15, lh = lane >> 4;
    // A fragments straight from global: a[m][ks]
    short8v a[4][4];
#pragma unroll
    for (int m = 0; m < 4; ++m) {
        int gr = m0 + wr * 64 + m * 16 + lr;
        if (gr >= N_NODES) gr = N_NODES - 1;
#pragma unroll
        for (int ks = 0; ks < 4; ++ks) {
            uint4 v = Aq[gr * 16 + ks * 4 + lh];
            a[m][ks] = *reinterpret_cast<const short8v*>(&v);
        }
    }
    const uint4* Bp = Bq + (size_t)((p < 4) ? (1 + p) : 0) * NCOLS * 16;
    f32x4 zero = {0.f, 0.f, 0.f, 0.f};
    f32x4 hx[4][2], hb[4][2];
    int srow = t >> 4, sslot = t & 15;
#pragma unroll
    for (int chunk = 0; chunk < 3; ++chunk) {
        int n0 = chunk * 128;
        f32x4 acc[4][2];
#pragma unroll
        for (int m = 0; m < 4; ++m)
#pragma unroll
            for (int n = 0; n < 2; ++n) acc[m][n] = zero;
#pragma unroll
        for (int ks = 0; ks < 4; ++ks) {
            short8v b[2];
#pragma unroll
            for (int n = 0; n < 2; ++n) {
                int row = n0 + wc * 32 + n * 16 + lr;
                b[n] = *reinterpret_cast<const short8v*>(&Bp[row * 16 + ks * 4 + lh]);
            }
#pragma unroll
            for (int m = 0; m < 4; ++m)
#pragma unroll
                for (int n = 0; n < 2; ++n)
                    acc[m][n] = __builtin_amdgcn_mfma_f32_16x16x32_bf16(a[m][ks], b[n], acc[m][n], 0, 0, 0);
        }
        if (p < 4) {
            __syncthreads();  // previous chunk's Cs reads done
#pragma unroll
            for (int m = 0; m < 4; ++m)
#pragma unroll
                for (int reg = 0; reg < 4; ++reg) {
                    int row = wr * 64 + m * 16 + lh * 4 + reg;
#pragma unroll
                    for (int n = 0; n < 2; ++n) {
                        int col = wc * 32 + n * 16 + lr;
                        Cs[row * 128 + (col ^ ((lh & 1) << 4))] = f2b(acc[m][n][reg]);
                    }
                }
            __syncthreads();
#pragma unroll
            for (int it = 0; it < 4; ++it) {
                int row = it * 32 + srow;
                int gr = m0 + row;
                if (gr < N_NODES) {
                    uint4 v = *reinterpret_cast<const uint4*>(
                        &Cs[row * 128 + ((sslot * 8) ^ (((row >> 2) & 1) << 4))]);
                    if (chunk == 0)
                        *reinterpret_cast<uint4*>(&xrp[((size_t)p * N_NODES + gr) * 128 + sslot * 8]) = v;
                    else if (chunk == 1)
                        *reinterpret_cast<uint4*>(&gbp[(size_t)gr * 1024 + p * 256 + sslot * 8]) = v;
                    else
                        *reinterpret_cast<uint4*>(&gbp[(size_t)gr * 1024 + p * 256 + 128 + sslot * 8]) = v;
                }
            }
        } else {
            if (chunk == 0) {
#pragma unroll
                for (int m = 0; m < 4; ++m)
#pragma unroll
                    for (int n = 0; n < 2; ++n) hx[m][n] = acc[m][n];
            } else if (chunk == 1) {
#pragma unroll
                for (int m = 0; m < 4; ++m)
#pragma unroll
                    for (int n = 0; n < 2; ++n) hb[m][n] = acc[m][n];
            } else {
#pragma unroll
                for (int m = 0; m < 4; ++m)
#pragma unroll
                    for (int reg = 0; reg < 4; ++reg) {
                        int row = wr * 64 + m * 16 + lh * 4 + reg;
#pragma unroll
                        for (int n = 0; n < 2; ++n) {
                            int col = wc * 32 + n * 16 + lr;
                            float h = fmaxf(acc[m][n][reg] * hx[m][n][reg] + hb[m][n][reg], 0.f);
                            Cs[row * 128 + (col ^ ((lh & 1) << 4))] = f2b(h);
                        }
                    }
            }
        }
    }
    if (p == 4) {
        __syncthreads();
#pragma unroll
        for (int it = 0; it < 4; ++it) {
            int row = it * 32 + srow;
            int gr = m0 + row;
            if (gr < N_NODES) {
                uint4 v = *reinterpret_cast<const uint4*>(
                    &Cs[row * 128 + ((sslot * 8) ^ (((row >> 2) & 1) << 4))]);
                *reinterpret_cast<uint4*>(&selfb[(size_t)gr * D + sslot * 8]) = v;
            }
        }
    }
}

// ---------------- agg: wave/node; quarter-wave per relation; uint4 gathers; 4 streams in flight
__global__ __launch_bounds__(256) void film_agg3(const u16* __restrict__ selfb, const u16* __restrict__ xrp,
                                                 const u16* __restrict__ gbp,
                                                 const int* __restrict__ offs, const int* __restrict__ esrc,
                                                 float* __restrict__ acc) {
    int t = threadIdx.x;
    int n = blockIdx.x * 4 + (t >> 6);
    int lane = t & 63;
    int cq = lane & 15;        // col quad: cols cq*8 .. cq*8+7
    int rel = lane >> 4;       // quarter-wave owns one relation
    float h[8];
#pragma unroll
    for (int j = 0; j < 8; ++j) h[j] = 0.f;
    int seg = n * R_REL + rel;
    int beg = offs[seg], end = offs[seg + 1];
    if (beg < end) {
        uint4 bv = *reinterpret_cast<const uint4*>(&gbp[(size_t)n * 1024 + rel * 256 + cq * 8]);
        uint4 gv = *reinterpret_cast<const uint4*>(&gbp[(size_t)n * 1024 + rel * 256 + 128 + cq * 8]);
        const u16* bp = (const u16*)&bv;
        const u16* gp = (const u16*)&gv;
        float be[8], ga[8];
#pragma unroll
        for (int j = 0; j < 8; ++j) { be[j] = b2f(bp[j]); ga[j] = b2f(gp[j]); }
        const u16* X = xrp + (size_t)rel * N_NODES * D;
        float s[8];
#pragma unroll
        for (int j = 0; j < 8; ++j) s[j] = 0.f;
        for (int i = beg; i < end; ++i) {
            int src = esrc[i];
            uint4 xv = *reinterpret_cast<const uint4*>(&X[(size_t)src * D + cq * 8]);
            const u16* xp = (const u16*)&xv;
#pragma unroll
            for (int j = 0; j < 8; ++j) s[j] += fmaxf(ga[j] * b2f(xp[j]) + be[j], 0.f);
        }
        float inv = 1.f / (float)(end - beg);
#pragma unroll
        for (int j = 0; j < 8; ++j) h[j] = s[j] * inv;
    }
    // combine the 4 relation quarters, then add self
#pragma unroll
    for (int j = 0; j < 8; ++j) {
        h[j] += __shfl_xor(h[j], 16);
        h[j] += __shfl_xor(h[j], 32);
    }
    uint4 sv = *reinterpret_cast<const uint4*>(&selfb[(size_t)n * D + cq * 8]);
    const u16* sp = (const u16*)&sv;
#pragma unroll
    for (int j = 0; j < 8; ++j) h[j] += b2f(sp[j]);
    if (lane < 16) {
        float4 o0 = make_float4(h[0], h[1], h[2], h[3]);
        float4 o1 = make_float4(h[4], h[5], h[6], h[7]);
        *reinterpret_cast<float4*>(&acc[(size_t)n * D + cq * 8]) = o0;
        *reinterpret_cast<float4*>(&acc[(size_t)n * D + cq * 8 + 4]) = o1;
    }
}

// ---------------- batchnorm stats
__global__ __launch_bounds__(256) void bn_stats2(const float* __restrict__ acc, float* __restrict__ sums) {
    __shared__ float sm[256], sm2[256];
    int t = threadIdx.x;
    int c = t & 127, half = t >> 7;
    int rows = (N_NODES + gridDim.x - 1) / gridDim.x;
    int nb = blockIdx.x * rows;
    int n1 = min(nb + rows, N_NODES);
    float s = 0.f, s2 = 0.f;
    for (int n = nb + half; n < n1; n += 2) {
        float v = acc[n * D + c];
        s += v;
        s2 += v * v;
    }
    sm[t] = s; sm2[t] = s2;
    __syncthreads();
    if (t < 128) {
        atomicAdd(&sums[c], sm[t] + sm[t + 128]);
        atomicAdd(&sums[128 + c], sm2[t] + sm2[t + 128]);
    }
}

// ---------------- batchnorm apply -> bf16 next-layer input
__global__ void bn_apply(const float* __restrict__ acc, const float* __restrict__ sums,
                         const float* __restrict__ w, const float* __restrict__ b,
                         u16* __restrict__ hb16) {
    int idx = blockIdx.x * 256 + threadIdx.x;
    if (idx >= N_NODES * D) return;
    int c = idx & 127;
    const float invn = 1.f / (float)N_NODES;
    float mu = sums[c] * invn;
    float var = sums[128 + c] * invn - mu * mu;
    float rs = rsqrtf(var + BN_EPS);
    hb16[idx] = f2b((acc[idx] - mu) * rs * w[c] + b[c]);
}

// ---------------- head
__global__ __launch_bounds__(128) void head_k(const u16* __restrict__ h, const float* __restrict__ w1,
                                              const float* __restrict__ b1, const float* __restrict__ w2,
                                              const float* __restrict__ b2, float* __restrict__ out) {
    __shared__ float hrow[128];
    __shared__ float part[128];
    __shared__ float mid[32];
    int n = blockIdx.x, t = threadIdx.x;
    hrow[t] = b2f(h[n * D + t]);
    __syncthreads();
    int m = t & 31, q = t >> 5;
    float p = 0.f;
#pragma unroll 8
    for (int k = q * 32; k < q * 32 + 32; ++k) p += hrow[k] * w1[k * 32 + m];
    part[t] = p;
    __syncthreads();
    if (t < 32) {
        float v = part[t] + part[t + 32] + part[t + 64] + part[t + 96] + b1[t];
        mid[t] = v > 0.f ? v : 0.2f * v;
    }
    __syncthreads();
    if (t < 40) {
        float o = b2[t];
#pragma unroll 8
        for (int mm = 0; mm < 32; ++mm) o += mid[mm] * w2[mm * 40 + t];
        out[n * 40 + t] = o;
    }
}

extern "C" void kernel_launch(void* const* d_in, const int* in_sizes, int n_in,
                              void* d_out, int out_size, void* d_ws, size_t ws_size,
                              hipStream_t stream) {
    const float* x    = (const float*)d_in[0];
    const int*   ei   = (const int*)d_in[1];
    const int*   et   = (const int*)d_in[2];
    const float* Wsk  = (const float*)d_in[3];
    const float* Wfsk = (const float*)d_in[4];
    const float* Wr   = (const float*)d_in[5];
    const float* Wf   = (const float*)d_in[6];
    const float* bnw  = (const float*)d_in[7];
    const float* bnb  = (const float*)d_in[8];
    const float* w1   = (const float*)d_in[9];
    const float* b1   = (const float*)d_in[10];
    const float* w2   = (const float*)d_in[11];
    const float* b2   = (const float*)d_in[12];
    const int* src = ei;
    const int* dst = ei + N_EDGES;

    char* ws = (char*)d_ws;
    size_t off = 0;
    auto alloc = [&](size_t bytes) -> void* {
        void* p = ws + off;
        off += (bytes + 255) & ~(size_t)255;
        return p;
    };
    u16*   Wpb  = (u16*)alloc((size_t)L_LAYERS * 5 * NCOLS * D * 2);
    u16*   inb  = (u16*)alloc((size_t)N_NODES * D * 2);
    float* acc  = (float*)alloc((size_t)N_NODES * D * 4);
    int*   cnt    = (int*)alloc((size_t)M_SEG * 4);     // contiguous with bns: one memset
    float* bns    = (float*)alloc((size_t)L_LAYERS * 256 * 4);
    int*   offs   = (int*)alloc((size_t)(M_SEG + 1) * 4);
    int*   esrc   = (int*)alloc((size_t)N_EDGES * 4);
    int*   rank   = (int*)alloc((size_t)N_EDGES * 4);
    int*   bsum   = (int*)alloc(1024 * 4);
    int*   bsumex = (int*)alloc(1024 * 4);
    u16*   xrp    = (u16*)alloc((size_t)R_REL * N_NODES * D * 2);   // 51.2 MB compact gather planes
    u16*   gbp    = (u16*)alloc((size_t)N_NODES * R_REL * 256 * 2); // 102.4 MB node-major beta|gamma
    u16*   selfb  = (u16*)alloc((size_t)N_NODES * D * 2);           // 12.8 MB

    hipMemsetAsync(cnt, 0, (size_t)M_SEG * 4 + (size_t)L_LAYERS * 1024, stream);

    pack_w<<<(L_LAYERS * 5 * NCOLS * D + 255) / 256, 256, 0, stream>>>(Wsk, Wfsk, Wr, Wf, Wpb);
    cvt_bf16<<<(N_NODES * D + 255) / 256, 256, 0, stream>>>(x, inb);
    hist_k<<<(N_EDGES + 255) / 256, 256, 0, stream>>>(dst, et, cnt, rank);
    scan_a<<<NB_SCAN, 256, 0, stream>>>(cnt, bsum);
    scan_b<<<1, 1024, 0, stream>>>(bsum, bsumex, offs);
    scan_c<<<NB_SCAN, 256, 0, stream>>>(cnt, bsumex, offs);
    scatter_k<<<(N_EDGES + 255) / 256, 256, 0, stream>>>(src, dst, et, offs, rank, esrc);

    const int nbm = (N_NODES + 127) / 128;  // 391
    for (int l = 0; l < L_LAYERS; ++l) {
        gemm_all<<<dim3(nbm, 5), 512, 0, stream>>>((const uint4*)inb,
                                                   (const uint4*)(Wpb + (size_t)(l * 5) * NCOLS * D),
                                                   xrp, gbp, selfb);
        film_agg3<<<N_NODES / 4, 256, 0, stream>>>(selfb, xrp, gbp, offs, esrc, acc);
        bn_stats2<<<256, 256, 0, stream>>>(acc, bns + l * 256);
        bn_apply<<<(N_NODES * D + 255) / 256, 256, 0, stream>>>(acc, bns + l * 256, bnw + l * D, bnb + l * D, inb);
    }
    head_k<<<N_NODES, 128, 0, stream>>>(inb, w1, b1, w2, b2, (float*)d_out);
}

// Round 9
// 762.287 us; speedup vs baseline: 1.0630x; 1.0630x over previous
//
#include <hip/hip_runtime.h>

#define N_NODES 50000
#define N_EDGES 800000
#define D 128
#define R_REL 4
#define L_LAYERS 3
#define M_SEG (N_NODES * R_REL)
#define NCOLS 384
#define BN_EPS 1e-5f

typedef unsigned short u16;
typedef __attribute__((ext_vector_type(8))) short short8v;
typedef __attribute__((ext_vector_type(4))) float f32x4;

static __device__ __forceinline__ u16 f2b(float f) {
    union { float f; unsigned int u; } a; a.f = f;
    unsigned int u = a.u;
    return (u16)((u + 0x7FFFu + ((u >> 16) & 1u)) >> 16);
}
static __device__ __forceinline__ float b2f(u16 b) {
    union { unsigned int u; float f; } a; a.u = ((unsigned int)b) << 16;
    return a.f;
}

// LDS-only barrier: orders ds ops without draining global stores (avoids the
// vmcnt(0) __syncthreads emits). All barriers in gemm_all order ONLY LDS.
static __device__ __forceinline__ void lds_barrier() {
    asm volatile("s_waitcnt lgkmcnt(0)" ::: "memory");
    __builtin_amdgcn_sched_barrier(0);
    __builtin_amdgcn_s_barrier();
}

// ---------------- weight packing: Wpb[(l*5+p)][j=0..383][k=0..127] bf16 (transposed)
__global__ void pack_w(const float* __restrict__ Wsk, const float* __restrict__ Wfsk,
                       const float* __restrict__ Wr, const float* __restrict__ Wf,
                       u16* __restrict__ Wpb) {
    int idx = blockIdx.x * 256 + threadIdx.x;
    if (idx >= L_LAYERS * 5 * NCOLS * D) return;
    int k = idx & 127;
    int rem = idx >> 7;
    int j = rem % NCOLS;
    int lp = rem / NCOLS;
    int l = lp / 5, p = lp % 5;
    float v;
    if (p == 0) {
        v = (j < D) ? Wsk[(l * D + k) * D + j] : Wfsk[(l * D + k) * 2 * D + (j - D)];
    } else {
        int r = p - 1;
        v = (j < D) ? Wr[((l * R_REL + r) * D + k) * D + j]
                    : Wf[((l * R_REL + r) * D + k) * 2 * D + (j - D)];
    }
    Wpb[idx] = f2b(v);
}

__global__ void cvt_bf16(const float* __restrict__ x, u16* __restrict__ xb) {
    int idx = blockIdx.x * 256 + threadIdx.x;
    if (idx >= N_NODES * D) return;
    xb[idx] = f2b(x[idx]);
}

// ---------------- CSR build over segments seg = dst*R + etype (rank captured here)
__global__ void hist_k(const int* __restrict__ dst, const int* __restrict__ et,
                       int* __restrict__ cnt, int* __restrict__ rank) {
    int e = blockIdx.x * 256 + threadIdx.x;
    if (e >= N_EDGES) return;
    rank[e] = atomicAdd(&cnt[dst[e] * R_REL + et[e]], 1);
}

__global__ void scan_a(const int* __restrict__ cnt, int* __restrict__ bsum) {
    __shared__ int sm[256];
    int t = threadIdx.x;
    int idx = blockIdx.x * 256 + t;
    sm[t] = (idx < M_SEG) ? cnt[idx] : 0;
    __syncthreads();
    for (int s = 128; s > 0; s >>= 1) {
        if (t < s) sm[t] += sm[t + s];
        __syncthreads();
    }
    if (t == 0) bsum[blockIdx.x] = sm[0];
}

#define NB_SCAN 782  // ceil(200000/256)
__global__ void scan_b(const int* __restrict__ bsum, int* __restrict__ bsumex, int* __restrict__ offs) {
    __shared__ int sm[1024];
    int t = threadIdx.x;
    int v = (t < NB_SCAN) ? bsum[t] : 0;
    sm[t] = v;
    __syncthreads();
    for (int d = 1; d < 1024; d <<= 1) {
        int add = (t >= d) ? sm[t - d] : 0;
        __syncthreads();
        sm[t] += add;
        __syncthreads();
    }
    if (t < NB_SCAN) bsumex[t] = sm[t] - v;
    if (t == NB_SCAN - 1) offs[M_SEG] = sm[t];
}

__global__ void scan_c(const int* __restrict__ cnt, const int* __restrict__ bsumex, int* __restrict__ offs) {
    __shared__ int sm[256];
    int t = threadIdx.x;
    int idx = blockIdx.x * 256 + t;
    int v = (idx < M_SEG) ? cnt[idx] : 0;
    sm[t] = v;
    __syncthreads();
    for (int d = 1; d < 256; d <<= 1) {
        int add = (t >= d) ? sm[t - d] : 0;
        __syncthreads();
        sm[t] += add;
        __syncthreads();
    }
    if (idx < M_SEG) offs[idx] = bsumex[blockIdx.x] + sm[t] - v;
}

__global__ void scatter_k(const int* __restrict__ src, const int* __restrict__ dst,
                          const int* __restrict__ et, const int* __restrict__ offs,
                          const int* __restrict__ rank, int* __restrict__ esrc) {
    int e = blockIdx.x * 256 + threadIdx.x;
    if (e >= N_EDGES) return;
    int seg = dst[e] * R_REL + et[e];
    esrc[offs[seg] + rank[e]] = src[e];
}

// ============ unified per-layer GEMM, grid (391, 5):
// p<4: relation planes -> xrp[p][N][128] (xr) and gbp[N][p][256] (beta|gamma)
// p==4: self FiLM fused -> selfb[N][128] = relu(gamma_s * xsk + beta_s)
// As staged once (coalesced); all barriers are LDS-only (global stores never drained).
__global__ __launch_bounds__(512) void gemm_all(const uint4* __restrict__ Aq,
                                                const uint4* __restrict__ Bq,   // layer base [5*384][16]
                                                u16* __restrict__ xrp, u16* __restrict__ gbp,
                                                u16* __restrict__ selfb) {
    __shared__ uint4 As[128 * 16];
    __shared__ u16 Cs[128 * 128];
    int t = threadIdx.x;
    int m0 = blockIdx.x * 128;
    int p = blockIdx.y;
#pragma unroll
    for (int i = 0; i < 4; ++i) {
        int idx = i * 512 + t;
        int row = idx >> 4, kk = idx & 15;
        int gr = m0 + row;
        if (gr >= N_NODES) gr = N_NODES - 1;
        As[(row << 4) + (kk ^ (row & 7))] = Aq[gr * 16 + kk];
    }
    lds_barrier();
    int lane = t & 63, w = t >> 6;
    int wr = w >> 2, wc = w & 3;
    int lr = lane & 15, lh = lane >> 4;
    short8v a[4][4];
#pragma unroll
    for (int m = 0; m < 4; ++m) {
        int row = wr * 64 + m * 16 + lr;
#pragma unroll
        for (int ks = 0; ks < 4; ++ks)
            a[m][ks] = *reinterpret_cast<const short8v*>(&As[(row << 4) + ((ks * 4 + lh) ^ (row & 7))]);
    }
    const uint4* Bp = Bq + (size_t)((p < 4) ? (1 + p) : 0) * NCOLS * 16;
    f32x4 zero = {0.f, 0.f, 0.f, 0.f};
    f32x4 hx[4][2], hb[4][2];
    int srow = t >> 4, sslot = t & 15;
#pragma unroll
    for (int chunk = 0; chunk < 3; ++chunk) {
        int n0 = chunk * 128;
        f32x4 acc[4][2];
#pragma unroll
        for (int m = 0; m < 4; ++m)
#pragma unroll
            for (int n = 0; n < 2; ++n) acc[m][n] = zero;
#pragma unroll
        for (int ks = 0; ks < 4; ++ks) {
            short8v b[2];
#pragma unroll
            for (int n = 0; n < 2; ++n) {
                int row = n0 + wc * 32 + n * 16 + lr;
                b[n] = *reinterpret_cast<const short8v*>(&Bp[row * 16 + ks * 4 + lh]);
            }
#pragma unroll
            for (int m = 0; m < 4; ++m)
#pragma unroll
                for (int n = 0; n < 2; ++n)
                    acc[m][n] = __builtin_amdgcn_mfma_f32_16x16x32_bf16(a[m][ks], b[n], acc[m][n], 0, 0, 0);
        }
        if (p < 4) {
            lds_barrier();  // previous chunk's Cs reads done
#pragma unroll
            for (int m = 0; m < 4; ++m)
#pragma unroll
                for (int reg = 0; reg < 4; ++reg) {
                    int row = wr * 64 + m * 16 + lh * 4 + reg;
#pragma unroll
                    for (int n = 0; n < 2; ++n) {
                        int col = wc * 32 + n * 16 + lr;
                        Cs[row * 128 + (col ^ ((lh & 1) << 4))] = f2b(acc[m][n][reg]);
                    }
                }
            lds_barrier();
#pragma unroll
            for (int it = 0; it < 4; ++it) {
                int row = it * 32 + srow;
                int gr = m0 + row;
                if (gr < N_NODES) {
                    uint4 v = *reinterpret_cast<const uint4*>(
                        &Cs[row * 128 + ((sslot * 8) ^ (((row >> 2) & 1) << 4))]);
                    if (chunk == 0)
                        *reinterpret_cast<uint4*>(&xrp[((size_t)p * N_NODES + gr) * 128 + sslot * 8]) = v;
                    else if (chunk == 1)
                        *reinterpret_cast<uint4*>(&gbp[(size_t)gr * 1024 + p * 256 + sslot * 8]) = v;
                    else
                        *reinterpret_cast<uint4*>(&gbp[(size_t)gr * 1024 + p * 256 + 128 + sslot * 8]) = v;
                }
            }
        } else {
            if (chunk == 0) {
#pragma unroll
                for (int m = 0; m < 4; ++m)
#pragma unroll
                    for (int n = 0; n < 2; ++n) hx[m][n] = acc[m][n];
            } else if (chunk == 1) {
#pragma unroll
                for (int m = 0; m < 4; ++m)
#pragma unroll
                    for (int n = 0; n < 2; ++n) hb[m][n] = acc[m][n];
            } else {
#pragma unroll
                for (int m = 0; m < 4; ++m)
#pragma unroll
                    for (int reg = 0; reg < 4; ++reg) {
                        int row = wr * 64 + m * 16 + lh * 4 + reg;
#pragma unroll
                        for (int n = 0; n < 2; ++n) {
                            int col = wc * 32 + n * 16 + lr;
                            float h = fmaxf(acc[m][n][reg] * hx[m][n][reg] + hb[m][n][reg], 0.f);
                            Cs[row * 128 + (col ^ ((lh & 1) << 4))] = f2b(h);
                        }
                    }
            }
        }
    }
    if (p == 4) {
        lds_barrier();
#pragma unroll
        for (int it = 0; it < 4; ++it) {
            int row = it * 32 + srow;
            int gr = m0 + row;
            if (gr < N_NODES) {
                uint4 v = *reinterpret_cast<const uint4*>(
                    &Cs[row * 128 + ((sslot * 8) ^ (((row >> 2) & 1) << 4))]);
                *reinterpret_cast<uint4*>(&selfb[(size_t)gr * D + sslot * 8]) = v;
            }
        }
    }
}

// ---------------- agg: wave/node; quarter-wave per relation; uint4 gathers; 4 streams in flight
__global__ __launch_bounds__(256) void film_agg3(const u16* __restrict__ selfb, const u16* __restrict__ xrp,
                                                 const u16* __restrict__ gbp,
                                                 const int* __restrict__ offs, const int* __restrict__ esrc,
                                                 float* __restrict__ acc) {
    int t = threadIdx.x;
    int n = blockIdx.x * 4 + (t >> 6);
    int lane = t & 63;
    int cq = lane & 15;        // col quad: cols cq*8 .. cq*8+7
    int rel = lane >> 4;       // quarter-wave owns one relation
    float h[8];
#pragma unroll
    for (int j = 0; j < 8; ++j) h[j] = 0.f;
    int seg = n * R_REL + rel;
    int beg = offs[seg], end = offs[seg + 1];
    if (beg < end) {
        uint4 bv = *reinterpret_cast<const uint4*>(&gbp[(size_t)n * 1024 + rel * 256 + cq * 8]);
        uint4 gv = *reinterpret_cast<const uint4*>(&gbp[(size_t)n * 1024 + rel * 256 + 128 + cq * 8]);
        const u16* bp = (const u16*)&bv;
        const u16* gp = (const u16*)&gv;
        float be[8], ga[8];
#pragma unroll
        for (int j = 0; j < 8; ++j) { be[j] = b2f(bp[j]); ga[j] = b2f(gp[j]); }
        const u16* X = xrp + (size_t)rel * N_NODES * D;
        float s[8];
#pragma unroll
        for (int j = 0; j < 8; ++j) s[j] = 0.f;
        for (int i = beg; i < end; ++i) {
            int src = esrc[i];
            uint4 xv = *reinterpret_cast<const uint4*>(&X[(size_t)src * D + cq * 8]);
            const u16* xp = (const u16*)&xv;
#pragma unroll
            for (int j = 0; j < 8; ++j) s[j] += fmaxf(ga[j] * b2f(xp[j]) + be[j], 0.f);
        }
        float inv = 1.f / (float)(end - beg);
#pragma unroll
        for (int j = 0; j < 8; ++j) h[j] = s[j] * inv;
    }
    // combine the 4 relation quarters, then add self
#pragma unroll
    for (int j = 0; j < 8; ++j) {
        h[j] += __shfl_xor(h[j], 16);
        h[j] += __shfl_xor(h[j], 32);
    }
    uint4 sv = *reinterpret_cast<const uint4*>(&selfb[(size_t)n * D + cq * 8]);
    const u16* sp = (const u16*)&sv;
#pragma unroll
    for (int j = 0; j < 8; ++j) h[j] += b2f(sp[j]);
    if (lane < 16) {
        float4 o0 = make_float4(h[0], h[1], h[2], h[3]);
        float4 o1 = make_float4(h[4], h[5], h[6], h[7]);
        *reinterpret_cast<float4*>(&acc[(size_t)n * D + cq * 8]) = o0;
        *reinterpret_cast<float4*>(&acc[(size_t)n * D + cq * 8 + 4]) = o1;
    }
}

// ---------------- batchnorm stats
__global__ __launch_bounds__(256) void bn_stats2(const float* __restrict__ acc, float* __restrict__ sums) {
    __shared__ float sm[256], sm2[256];
    int t = threadIdx.x;
    int c = t & 127, half = t >> 7;
    int rows = (N_NODES + gridDim.x - 1) / gridDim.x;
    int nb = blockIdx.x * rows;
    int n1 = min(nb + rows, N_NODES);
    float s = 0.f, s2 = 0.f;
    for (int n = nb + half; n < n1; n += 2) {
        float v = acc[n * D + c];
        s += v;
        s2 += v * v;
    }
    sm[t] = s; sm2[t] = s2;
    __syncthreads();
    if (t < 128) {
        atomicAdd(&sums[c], sm[t] + sm[t + 128]);
        atomicAdd(&sums[128 + c], sm2[t] + sm2[t + 128]);
    }
}

// ---------------- batchnorm apply -> bf16 next-layer input
__global__ void bn_apply(const float* __restrict__ acc, const float* __restrict__ sums,
                         const float* __restrict__ w, const float* __restrict__ b,
                         u16* __restrict__ hb16) {
    int idx = blockIdx.x * 256 + threadIdx.x;
    if (idx >= N_NODES * D) return;
    int c = idx & 127;
    const float invn = 1.f / (float)N_NODES;
    float mu = sums[c] * invn;
    float var = sums[128 + c] * invn - mu * mu;
    float rs = rsqrtf(var + BN_EPS);
    hb16[idx] = f2b((acc[idx] - mu) * rs * w[c] + b[c]);
}

// ---------------- head
__global__ __launch_bounds__(128) void head_k(const u16* __restrict__ h, const float* __restrict__ w1,
                                              const float* __restrict__ b1, const float* __restrict__ w2,
                                              const float* __restrict__ b2, float* __restrict__ out) {
    __shared__ float hrow[128];
    __shared__ float part[128];
    __shared__ float mid[32];
    int n = blockIdx.x, t = threadIdx.x;
    hrow[t] = b2f(h[n * D + t]);
    __syncthreads();
    int m = t & 31, q = t >> 5;
    float p = 0.f;
#pragma unroll 8
    for (int k = q * 32; k < q * 32 + 32; ++k) p += hrow[k] * w1[k * 32 + m];
    part[t] = p;
    __syncthreads();
    if (t < 32) {
        float v = part[t] + part[t + 32] + part[t + 64] + part[t + 96] + b1[t];
        mid[t] = v > 0.f ? v : 0.2f * v;
    }
    __syncthreads();
    if (t < 40) {
        float o = b2[t];
#pragma unroll 8
        for (int mm = 0; mm < 32; ++mm) o += mid[mm] * w2[mm * 40 + t];
        out[n * 40 + t] = o;
    }
}

extern "C" void kernel_launch(void* const* d_in, const int* in_sizes, int n_in,
                              void* d_out, int out_size, void* d_ws, size_t ws_size,
                              hipStream_t stream) {
    const float* x    = (const float*)d_in[0];
    const int*   ei   = (const int*)d_in[1];
    const int*   et   = (const int*)d_in[2];
    const float* Wsk  = (const float*)d_in[3];
    const float* Wfsk = (const float*)d_in[4];
    const float* Wr   = (const float*)d_in[5];
    const float* Wf   = (const float*)d_in[6];
    const float* bnw  = (const float*)d_in[7];
    const float* bnb  = (const float*)d_in[8];
    const float* w1   = (const float*)d_in[9];
    const float* b1   = (const float*)d_in[10];
    const float* w2   = (const float*)d_in[11];
    const float* b2   = (const float*)d_in[12];
    const int* src = ei;
    const int* dst = ei + N_EDGES;

    char* ws = (char*)d_ws;
    size_t off = 0;
    auto alloc = [&](size_t bytes) -> void* {
        void* p = ws + off;
        off += (bytes + 255) & ~(size_t)255;
        return p;
    };
    u16*   Wpb  = (u16*)alloc((size_t)L_LAYERS * 5 * NCOLS * D * 2);
    u16*   inb  = (u16*)alloc((size_t)N_NODES * D * 2);
    float* acc  = (float*)alloc((size_t)N_NODES * D * 4);
    int*   cnt    = (int*)alloc((size_t)M_SEG * 4);     // contiguous with bns: one memset
    float* bns    = (float*)alloc((size_t)L_LAYERS * 256 * 4);
    int*   offs   = (int*)alloc((size_t)(M_SEG + 1) * 4);
    int*   esrc   = (int*)alloc((size_t)N_EDGES * 4);
    int*   rank   = (int*)alloc((size_t)N_EDGES * 4);
    int*   bsum   = (int*)alloc(1024 * 4);
    int*   bsumex = (int*)alloc(1024 * 4);
    u16*   xrp    = (u16*)alloc((size_t)R_REL * N_NODES * D * 2);   // 51.2 MB compact gather planes
    u16*   gbp    = (u16*)alloc((size_t)N_NODES * R_REL * 256 * 2); // 102.4 MB node-major beta|gamma
    u16*   selfb  = (u16*)alloc((size_t)N_NODES * D * 2);           // 12.8 MB

    hipMemsetAsync(cnt, 0, (size_t)M_SEG * 4 + (size_t)L_LAYERS * 1024, stream);

    pack_w<<<(L_LAYERS * 5 * NCOLS * D + 255) / 256, 256, 0, stream>>>(Wsk, Wfsk, Wr, Wf, Wpb);
    cvt_bf16<<<(N_NODES * D + 255) / 256, 256, 0, stream>>>(x, inb);
    hist_k<<<(N_EDGES + 255) / 256, 256, 0, stream>>>(dst, et, cnt, rank);
    scan_a<<<NB_SCAN, 256, 0, stream>>>(cnt, bsum);
    scan_b<<<1, 1024, 0, stream>>>(bsum, bsumex, offs);
    scan_c<<<NB_SCAN, 256, 0, stream>>>(cnt, bsumex, offs);
    scatter_k<<<(N_EDGES + 255) / 256, 256, 0, stream>>>(src, dst, et, offs, rank, esrc);

    const int nbm = (N_NODES + 127) / 128;  // 391
    for (int l = 0; l < L_LAYERS; ++l) {
        gemm_all<<<dim3(nbm, 5), 512, 0, stream>>>((const uint4*)inb,
                                                   (const uint4*)(Wpb + (size_t)(l * 5) * NCOLS * D),
                                                   xrp, gbp, selfb);
        film_agg3<<<N_NODES / 4, 256, 0, stream>>>(selfb, xrp, gbp, offs, esrc, acc);
        bn_stats2<<<256, 256, 0, stream>>>(acc, bns + l * 256);
        bn_apply<<<(N_NODES * D + 255) / 256, 256, 0, stream>>>(acc, bns + l * 256, bnw + l * D, bnb + l * D, inb);
    }
    head_k<<<N_NODES, 128, 0, stream>>>(inb, w1, b1, w2, b2, (float*)d_out);
}

// Round 10
// 752.878 us; speedup vs baseline: 1.0763x; 1.0125x over previous
//
#include <hip/hip_runtime.h>

#define N_NODES 50000
#define N_EDGES 800000
#define D 128
#define R_REL 4
#define L_LAYERS 3
#define M_SEG (N_NODES * R_REL)
#define NCOLS 384
#define BN_EPS 1e-5f

typedef unsigned short u16;
typedef __attribute__((ext_vector_type(8))) short short8v;
typedef __attribute__((ext_vector_type(4))) float f32x4;

static __device__ __forceinline__ u16 f2b(float f) {
    union { float f; unsigned int u; } a; a.f = f;
    unsigned int u = a.u;
    return (u16)((u + 0x7FFFu + ((u >> 16) & 1u)) >> 16);
}
static __device__ __forceinline__ float b2f(u16 b) {
    union { unsigned int u; float f; } a; a.u = ((unsigned int)b) << 16;
    return a.f;
}

// LDS-only barrier: orders ds ops without draining global stores.
static __device__ __forceinline__ void lds_barrier() {
    asm volatile("s_waitcnt lgkmcnt(0)" ::: "memory");
    __builtin_amdgcn_sched_barrier(0);
    __builtin_amdgcn_s_barrier();
}

// ---------------- weight packing: Wpb[(l*5+p)][j=0..383][k=0..127] bf16 (transposed)
__global__ void pack_w(const float* __restrict__ Wsk, const float* __restrict__ Wfsk,
                       const float* __restrict__ Wr, const float* __restrict__ Wf,
                       u16* __restrict__ Wpb) {
    int idx = blockIdx.x * 256 + threadIdx.x;
    if (idx >= L_LAYERS * 5 * NCOLS * D) return;
    int k = idx & 127;
    int rem = idx >> 7;
    int j = rem % NCOLS;
    int lp = rem / NCOLS;
    int l = lp / 5, p = lp % 5;
    float v;
    if (p == 0) {
        v = (j < D) ? Wsk[(l * D + k) * D + j] : Wfsk[(l * D + k) * 2 * D + (j - D)];
    } else {
        int r = p - 1;
        v = (j < D) ? Wr[((l * R_REL + r) * D + k) * D + j]
                    : Wf[((l * R_REL + r) * D + k) * 2 * D + (j - D)];
    }
    Wpb[idx] = f2b(v);
}

__global__ void cvt_bf16(const float* __restrict__ x, u16* __restrict__ xb) {
    int idx = blockIdx.x * 256 + threadIdx.x;
    if (idx >= N_NODES * D) return;
    xb[idx] = f2b(x[idx]);
}

// ---------------- CSR build over segments seg = dst*R + etype (rank captured here)
__global__ void hist_k(const int* __restrict__ dst, const int* __restrict__ et,
                       int* __restrict__ cnt, int* __restrict__ rank) {
    int e = blockIdx.x * 256 + threadIdx.x;
    if (e >= N_EDGES) return;
    rank[e] = atomicAdd(&cnt[dst[e] * R_REL + et[e]], 1);
}

__global__ void scan_a(const int* __restrict__ cnt, int* __restrict__ bsum) {
    __shared__ int sm[256];
    int t = threadIdx.x;
    int idx = blockIdx.x * 256 + t;
    sm[t] = (idx < M_SEG) ? cnt[idx] : 0;
    __syncthreads();
    for (int s = 128; s > 0; s >>= 1) {
        if (t < s) sm[t] += sm[t + s];
        __syncthreads();
    }
    if (t == 0) bsum[blockIdx.x] = sm[0];
}

#define NB_SCAN 782  // ceil(200000/256)
__global__ void scan_b(const int* __restrict__ bsum, int* __restrict__ bsumex, int* __restrict__ offs) {
    __shared__ int sm[1024];
    int t = threadIdx.x;
    int v = (t < NB_SCAN) ? bsum[t] : 0;
    sm[t] = v;
    __syncthreads();
    for (int d = 1; d < 1024; d <<= 1) {
        int add = (t >= d) ? sm[t - d] : 0;
        __syncthreads();
        sm[t] += add;
        __syncthreads();
    }
    if (t < NB_SCAN) bsumex[t] = sm[t] - v;
    if (t == NB_SCAN - 1) offs[M_SEG] = sm[t];
}

__global__ void scan_c(const int* __restrict__ cnt, const int* __restrict__ bsumex, int* __restrict__ offs) {
    __shared__ int sm[256];
    int t = threadIdx.x;
    int idx = blockIdx.x * 256 + t;
    int v = (idx < M_SEG) ? cnt[idx] : 0;
    sm[t] = v;
    __syncthreads();
    for (int d = 1; d < 256; d <<= 1) {
        int add = (t >= d) ? sm[t - d] : 0;
        __syncthreads();
        sm[t] += add;
        __syncthreads();
    }
    if (idx < M_SEG) offs[idx] = bsumex[blockIdx.x] + sm[t] - v;
}

__global__ void scatter_k(const int* __restrict__ src, const int* __restrict__ dst,
                          const int* __restrict__ et, const int* __restrict__ offs,
                          const int* __restrict__ rank, int* __restrict__ esrc) {
    int e = blockIdx.x * 256 + threadIdx.x;
    if (e >= N_EDGES) return;
    int seg = dst[e] * R_REL + et[e];
    esrc[offs[seg] + rank[e]] = src[e];
}

// ============ unified per-layer GEMM, grid (391, 5):
// p<4: xr -> xrp[p][N][128]; beta -> gbp[(2p)][N][128]; gamma -> gbp[(2p+1)][N][128]
// p==4: self FiLM fused -> selfb[N][128]
// All epilogue writes are sequential 256B-run streams (plane-major layouts).
__global__ __launch_bounds__(512) void gemm_all(const uint4* __restrict__ Aq,
                                                const uint4* __restrict__ Bq,   // layer base [5*384][16]
                                                u16* __restrict__ xrp, u16* __restrict__ gbp,
                                                u16* __restrict__ selfb) {
    __shared__ uint4 As[128 * 16];
    __shared__ u16 Cs[128 * 128];
    int t = threadIdx.x;
    int m0 = blockIdx.x * 128;
    int p = blockIdx.y;
#pragma unroll
    for (int i = 0; i < 4; ++i) {
        int idx = i * 512 + t;
        int row = idx >> 4, kk = idx & 15;
        int gr = m0 + row;
        if (gr >= N_NODES) gr = N_NODES - 1;
        As[(row << 4) + (kk ^ (row & 7))] = Aq[gr * 16 + kk];
    }
    lds_barrier();
    int lane = t & 63, w = t >> 6;
    int wr = w >> 2, wc = w & 3;
    int lr = lane & 15, lh = lane >> 4;
    short8v a[4][4];
#pragma unroll
    for (int m = 0; m < 4; ++m) {
        int row = wr * 64 + m * 16 + lr;
#pragma unroll
        for (int ks = 0; ks < 4; ++ks)
            a[m][ks] = *reinterpret_cast<const short8v*>(&As[(row << 4) + ((ks * 4 + lh) ^ (row & 7))]);
    }
    const uint4* Bp = Bq + (size_t)((p < 4) ? (1 + p) : 0) * NCOLS * 16;
    f32x4 zero = {0.f, 0.f, 0.f, 0.f};
    f32x4 hx[4][2], hb[4][2];
    int srow = t >> 4, sslot = t & 15;
#pragma unroll
    for (int chunk = 0; chunk < 3; ++chunk) {
        int n0 = chunk * 128;
        f32x4 acc[4][2];
#pragma unroll
        for (int m = 0; m < 4; ++m)
#pragma unroll
            for (int n = 0; n < 2; ++n) acc[m][n] = zero;
#pragma unroll
        for (int ks = 0; ks < 4; ++ks) {
            short8v b[2];
#pragma unroll
            for (int n = 0; n < 2; ++n) {
                int row = n0 + wc * 32 + n * 16 + lr;
                b[n] = *reinterpret_cast<const short8v*>(&Bp[row * 16 + ks * 4 + lh]);
            }
#pragma unroll
            for (int m = 0; m < 4; ++m)
#pragma unroll
                for (int n = 0; n < 2; ++n)
                    acc[m][n] = __builtin_amdgcn_mfma_f32_16x16x32_bf16(a[m][ks], b[n], acc[m][n], 0, 0, 0);
        }
        if (p < 4) {
            lds_barrier();  // previous chunk's Cs reads done
#pragma unroll
            for (int m = 0; m < 4; ++m)
#pragma unroll
                for (int reg = 0; reg < 4; ++reg) {
                    int row = wr * 64 + m * 16 + lh * 4 + reg;
#pragma unroll
                    for (int n = 0; n < 2; ++n) {
                        int col = wc * 32 + n * 16 + lr;
                        Cs[row * 128 + (col ^ ((lh & 1) << 4))] = f2b(acc[m][n][reg]);
                    }
                }
            lds_barrier();
            // plane-major destinations: all sequential streams
            u16* dstp = (chunk == 0) ? (xrp + (size_t)p * N_NODES * 128)
                      : (gbp + (size_t)(p * 2 + (chunk - 1)) * N_NODES * 128);
#pragma unroll
            for (int it = 0; it < 4; ++it) {
                int row = it * 32 + srow;
                int gr = m0 + row;
                if (gr < N_NODES) {
                    uint4 v = *reinterpret_cast<const uint4*>(
                        &Cs[row * 128 + ((sslot * 8) ^ (((row >> 2) & 1) << 4))]);
                    *reinterpret_cast<uint4*>(&dstp[(size_t)gr * 128 + sslot * 8]) = v;
                }
            }
        } else {
            if (chunk == 0) {
#pragma unroll
                for (int m = 0; m < 4; ++m)
#pragma unroll
                    for (int n = 0; n < 2; ++n) hx[m][n] = acc[m][n];
            } else if (chunk == 1) {
#pragma unroll
                for (int m = 0; m < 4; ++m)
#pragma unroll
                    for (int n = 0; n < 2; ++n) hb[m][n] = acc[m][n];
            } else {
#pragma unroll
                for (int m = 0; m < 4; ++m)
#pragma unroll
                    for (int reg = 0; reg < 4; ++reg) {
                        int row = wr * 64 + m * 16 + lh * 4 + reg;
#pragma unroll
                        for (int n = 0; n < 2; ++n) {
                            int col = wc * 32 + n * 16 + lr;
                            float h = fmaxf(acc[m][n][reg] * hx[m][n][reg] + hb[m][n][reg], 0.f);
                            Cs[row * 128 + (col ^ ((lh & 1) << 4))] = f2b(h);
                        }
                    }
            }
        }
    }
    if (p == 4) {
        lds_barrier();
#pragma unroll
        for (int it = 0; it < 4; ++it) {
            int row = it * 32 + srow;
            int gr = m0 + row;
            if (gr < N_NODES) {
                uint4 v = *reinterpret_cast<const uint4*>(
                    &Cs[row * 128 + ((sslot * 8) ^ (((row >> 2) & 1) << 4))]);
                *reinterpret_cast<uint4*>(&selfb[(size_t)gr * D + sslot * 8]) = v;
            }
        }
    }
}

// ---------------- agg: wave/node; quarter-wave per relation; uint4 gathers; 4 streams in flight
__global__ __launch_bounds__(256) void film_agg3(const u16* __restrict__ selfb, const u16* __restrict__ xrp,
                                                 const u16* __restrict__ gbp,
                                                 const int* __restrict__ offs, const int* __restrict__ esrc,
                                                 float* __restrict__ acc) {
    int t = threadIdx.x;
    int n = blockIdx.x * 4 + (t >> 6);
    int lane = t & 63;
    int cq = lane & 15;        // col quad: cols cq*8 .. cq*8+7
    int rel = lane >> 4;       // quarter-wave owns one relation
    float h[8];
#pragma unroll
    for (int j = 0; j < 8; ++j) h[j] = 0.f;
    int seg = n * R_REL + rel;
    int beg = offs[seg], end = offs[seg + 1];
    if (beg < end) {
        uint4 bv = *reinterpret_cast<const uint4*>(&gbp[((size_t)(rel * 2 + 0) * N_NODES + n) * 128 + cq * 8]);
        uint4 gv = *reinterpret_cast<const uint4*>(&gbp[((size_t)(rel * 2 + 1) * N_NODES + n) * 128 + cq * 8]);
        const u16* bp = (const u16*)&bv;
        const u16* gp = (const u16*)&gv;
        float be[8], ga[8];
#pragma unroll
        for (int j = 0; j < 8; ++j) { be[j] = b2f(bp[j]); ga[j] = b2f(gp[j]); }
        const u16* X = xrp + (size_t)rel * N_NODES * D;
        float s[8];
#pragma unroll
        for (int j = 0; j < 8; ++j) s[j] = 0.f;
        for (int i = beg; i < end; ++i) {
            int src = esrc[i];
            uint4 xv = *reinterpret_cast<const uint4*>(&X[(size_t)src * D + cq * 8]);
            const u16* xp = (const u16*)&xv;
#pragma unroll
            for (int j = 0; j < 8; ++j) s[j] += fmaxf(ga[j] * b2f(xp[j]) + be[j], 0.f);
        }
        float inv = 1.f / (float)(end - beg);
#pragma unroll
        for (int j = 0; j < 8; ++j) h[j] = s[j] * inv;
    }
    // combine the 4 relation quarters, then add self
#pragma unroll
    for (int j = 0; j < 8; ++j) {
        h[j] += __shfl_xor(h[j], 16);
        h[j] += __shfl_xor(h[j], 32);
    }
    uint4 sv = *reinterpret_cast<const uint4*>(&selfb[(size_t)n * D + cq * 8]);
    const u16* sp = (const u16*)&sv;
#pragma unroll
    for (int j = 0; j < 8; ++j) h[j] += b2f(sp[j]);
    if (lane < 16) {
        float4 o0 = make_float4(h[0], h[1], h[2], h[3]);
        float4 o1 = make_float4(h[4], h[5], h[6], h[7]);
        *reinterpret_cast<float4*>(&acc[(size_t)n * D + cq * 8]) = o0;
        *reinterpret_cast<float4*>(&acc[(size_t)n * D + cq * 8 + 4]) = o1;
    }
}

// ---------------- batchnorm stats
__global__ __launch_bounds__(256) void bn_stats2(const float* __restrict__ acc, float* __restrict__ sums) {
    __shared__ float sm[256], sm2[256];
    int t = threadIdx.x;
    int c = t & 127, half = t >> 7;
    int rows = (N_NODES + gridDim.x - 1) / gridDim.x;
    int nb = blockIdx.x * rows;
    int n1 = min(nb + rows, N_NODES);
    float s = 0.f, s2 = 0.f;
    for (int n = nb + half; n < n1; n += 2) {
        float v = acc[n * D + c];
        s += v;
        s2 += v * v;
    }
    sm[t] = s; sm2[t] = s2;
    __syncthreads();
    if (t < 128) {
        atomicAdd(&sums[c], sm[t] + sm[t + 128]);
        atomicAdd(&sums[128 + c], sm2[t] + sm2[t + 128]);
    }
}

// ---------------- batchnorm apply -> bf16 next-layer input
__global__ void bn_apply(const float* __restrict__ acc, const float* __restrict__ sums,
                         const float* __restrict__ w, const float* __restrict__ b,
                         u16* __restrict__ hb16) {
    int idx = blockIdx.x * 256 + threadIdx.x;
    if (idx >= N_NODES * D) return;
    int c = idx & 127;
    const float invn = 1.f / (float)N_NODES;
    float mu = sums[c] * invn;
    float var = sums[128 + c] * invn - mu * mu;
    float rs = rsqrtf(var + BN_EPS);
    hb16[idx] = f2b((acc[idx] - mu) * rs * w[c] + b[c]);
}

// ---------------- head
__global__ __launch_bounds__(128) void head_k(const u16* __restrict__ h, const float* __restrict__ w1,
                                              const float* __restrict__ b1, const float* __restrict__ w2,
                                              const float* __restrict__ b2, float* __restrict__ out) {
    __shared__ float hrow[128];
    __shared__ float part[128];
    __shared__ float mid[32];
    int n = blockIdx.x, t = threadIdx.x;
    hrow[t] = b2f(h[n * D + t]);
    __syncthreads();
    int m = t & 31, q = t >> 5;
    float p = 0.f;
#pragma unroll 8
    for (int k = q * 32; k < q * 32 + 32; ++k) p += hrow[k] * w1[k * 32 + m];
    part[t] = p;
    __syncthreads();
    if (t < 32) {
        float v = part[t] + part[t + 32] + part[t + 64] + part[t + 96] + b1[t];
        mid[t] = v > 0.f ? v : 0.2f * v;
    }
    __syncthreads();
    if (t < 40) {
        float o = b2[t];
#pragma unroll 8
        for (int mm = 0; mm < 32; ++mm) o += mid[mm] * w2[mm * 40 + t];
        out[n * 40 + t] = o;
    }
}

extern "C" void kernel_launch(void* const* d_in, const int* in_sizes, int n_in,
                              void* d_out, int out_size, void* d_ws, size_t ws_size,
                              hipStream_t stream) {
    const float* x    = (const float*)d_in[0];
    const int*   ei   = (const int*)d_in[1];
    const int*   et   = (const int*)d_in[2];
    const float* Wsk  = (const float*)d_in[3];
    const float* Wfsk = (const float*)d_in[4];
    const float* Wr   = (const float*)d_in[5];
    const float* Wf   = (const float*)d_in[6];
    const float* bnw  = (const float*)d_in[7];
    const float* bnb  = (const float*)d_in[8];
    const float* w1   = (const float*)d_in[9];
    const float* b1   = (const float*)d_in[10];
    const float* w2   = (const float*)d_in[11];
    const float* b2   = (const float*)d_in[12];
    const int* src = ei;
    const int* dst = ei + N_EDGES;

    char* ws = (char*)d_ws;
    size_t off = 0;
    auto alloc = [&](size_t bytes) -> void* {
        void* p = ws + off;
        off += (bytes + 255) & ~(size_t)255;
        return p;
    };
    u16*   Wpb  = (u16*)alloc((size_t)L_LAYERS * 5 * NCOLS * D * 2);
    u16*   inb  = (u16*)alloc((size_t)N_NODES * D * 2);
    float* acc  = (float*)alloc((size_t)N_NODES * D * 4);
    int*   cnt    = (int*)alloc((size_t)M_SEG * 4);     // contiguous with bns: one memset
    float* bns    = (float*)alloc((size_t)L_LAYERS * 256 * 4);
    int*   offs   = (int*)alloc((size_t)(M_SEG + 1) * 4);
    int*   esrc   = (int*)alloc((size_t)N_EDGES * 4);
    int*   rank   = (int*)alloc((size_t)N_EDGES * 4);
    int*   bsum   = (int*)alloc(1024 * 4);
    int*   bsumex = (int*)alloc(1024 * 4);
    u16*   xrp    = (u16*)alloc((size_t)R_REL * N_NODES * D * 2);     // 51.2 MB gather planes
    u16*   gbp    = (u16*)alloc((size_t)R_REL * 2 * N_NODES * D * 2); // 102.4 MB beta/gamma planes
    u16*   selfb  = (u16*)alloc((size_t)N_NODES * D * 2);             // 12.8 MB

    hipMemsetAsync(cnt, 0, (size_t)M_SEG * 4 + (size_t)L_LAYERS * 1024, stream);

    pack_w<<<(L_LAYERS * 5 * NCOLS * D + 255) / 256, 256, 0, stream>>>(Wsk, Wfsk, Wr, Wf, Wpb);
    cvt_bf16<<<(N_NODES * D + 255) / 256, 256, 0, stream>>>(x, inb);
    hist_k<<<(N_EDGES + 255) / 256, 256, 0, stream>>>(dst, et, cnt, rank);
    scan_a<<<NB_SCAN, 256, 0, stream>>>(cnt, bsum);
    scan_b<<<1, 1024, 0, stream>>>(bsum, bsumex, offs);
    scan_c<<<NB_SCAN, 256, 0, stream>>>(cnt, bsumex, offs);
    scatter_k<<<(N_EDGES + 255) / 256, 256, 0, stream>>>(src, dst, et, offs, rank, esrc);

    const int nbm = (N_NODES + 127) / 128;  // 391
    for (int l = 0; l < L_LAYERS; ++l) {
        gemm_all<<<dim3(nbm, 5), 512, 0, stream>>>((const uint4*)inb,
                                                   (const uint4*)(Wpb + (size_t)(l * 5) * NCOLS * D),
                                                   xrp, gbp, selfb);
        film_agg3<<<N_NODES / 4, 256, 0, stream>>>(selfb, xrp, gbp, offs, esrc, acc);
        bn_stats2<<<256, 256, 0, stream>>>(acc, bns + l * 256);
        bn_apply<<<(N_NODES * D + 255) / 256, 256, 0, stream>>>(acc, bns + l * 256, bnw + l * D, bnb + l * D, inb);
    }
    head_k<<<N_NODES, 128, 0, stream>>>(inb, w1, b1, w2, b2, (float*)d_out);
}